// Round 7
// baseline (1766.102 us; speedup 1.0000x reference)
//
#include <hip/hip_runtime.h>

// LSTM B=256, T=2048, H=128. One batch row per WG, 512 threads = 128 units
// x 4 K-quarters. Thread (unit,kq) holds the kq*32..kq*32+32 slice of ALL
// FOUR gate rows (i,f,z,o) of its unit: 64 packed half2, asm-pinned.
//
// Round-6 lesson: VALU-issue bound; v_dot2_f32_f16 measured ~quarter-rate
// (8 cyc/wave-instr) on gfx950 -> 0.25 MAC/lane/cyc, HALF of plain fp32 fma.
// This round: v_fma_mix_f32 (VOP3P, fp16 operands lo/hi-selected, fp32 acc,
// full-rate fp32 pipe) -> 128 fma_mix @2cyc = 256 cyc/wave vs 512 for dot2.
//
// Per step (ONE lgkmcnt-only barrier): 4x ds_read_b128 (fp16 h slice) ->
// 128 fma_mix -> 8 DPP quad_perm adds (VALU pipe butterfly) -> bias/x ->
// activations + cell update redundantly on quad lanes -> kq==0 writes h to
// double-buffered h_lds + fire-and-forget global h store. fc deferred to k2.

typedef _Float16 half2v __attribute__((ext_vector_type(2)));

constexpr int NB = 256;
constexpr int NT = 2048;
constexpr int NH = 128;

__device__ __forceinline__ float fexp2(float x) {
    float r;
    asm("v_exp_f32 %0, %1" : "=v"(r) : "v"(x));
    return r;
}
__device__ __forceinline__ float frcp(float x) {
    float r;
    asm("v_rcp_f32 %0, %1" : "=v"(r) : "v"(x));
    return r;
}
__device__ __forceinline__ float fsig(float x) {   // 1/(1+2^(-x*log2e))
    return frcp(1.f + fexp2(x * -1.44269504f));
}
__device__ __forceinline__ float ftanh(float x) {  // 2/(1+2^(-2x*log2e)) - 1
    return fmaf(2.f, frcp(1.f + fexp2(x * -2.88539008f)), -1.f);
}

// acc += w.lo*h.lo + w.hi*h.hi with fp16 operands, fp32 accumulate, on the
// full-rate fp32 VALU pipe (v_fma_mix_f32), replacing quarter-rate v_dot2.
__device__ __forceinline__ void mix2(float& acc, unsigned w, unsigned h) {
    asm("v_fma_mix_f32 %0, %1, %2, %0 op_sel:[0,0,0] op_sel_hi:[1,1,0]\n\t"
        "v_fma_mix_f32 %0, %1, %2, %0 op_sel:[1,1,0] op_sel_hi:[1,1,0]"
        : "+v"(acc)
        : "v"(w), "v"(h));
}

// v += (v from quad_perm<CTRL> lane) — pure VALU (DPP), no LDS pipe.
// 0xB1 = [1,0,3,2] (xor 1), 0x4E = [2,3,0,1] (xor 2).
template <int CTRL>
__device__ __forceinline__ float dpp_add(float v) {
    int s = __builtin_bit_cast(int, v);
    int p = __builtin_amdgcn_update_dpp(s, s, CTRL, 0xF, 0xF, false);
    return v + __builtin_bit_cast(float, p);
}

__device__ __forceinline__ unsigned packh2(float lo, float hi) {
    half2v p;
    p.x = (_Float16)lo;
    p.y = (_Float16)hi;
    return __builtin_bit_cast(unsigned, p);
}

__device__ __forceinline__ float dot2(unsigned int w, unsigned int h, float acc) {
    half2v a = __builtin_bit_cast(half2v, w);
    half2v b = __builtin_bit_cast(half2v, h);
#if __has_builtin(__builtin_amdgcn_fdot2)
    return __builtin_amdgcn_fdot2(a, b, acc, false);
#else
    float r;
    asm("v_dot2_f32_f16 %0, %1, %2, %3" : "=v"(r) : "v"(a), "v"(b), "v"(acc));
    return r;
#endif
}

// barrier with LDS visibility, NO vmcnt drain (fire-and-forget h stores
// stay off the 2048-iteration critical path)
__device__ __forceinline__ void barrier_lds() {
    asm volatile("s_waitcnt lgkmcnt(0)" ::: "memory");
    __builtin_amdgcn_s_barrier();
    asm volatile("" ::: "memory");
}

template <bool DEFER_FC>
__global__ __launch_bounds__(512) __attribute__((amdgpu_waves_per_eu(2, 2)))
void lstm_k1(const float* __restrict__ x, const float* __restrict__ W_ih,
             const float* __restrict__ W_hh, const float* __restrict__ b_ih,
             const float* __restrict__ b_hh, const float* __restrict__ fc_w,
             const float* __restrict__ fc_b, float* __restrict__ out,
             _Float16* __restrict__ hws) {
    __shared__ __align__(16) float    x_lds[NT];
    __shared__ __align__(16) _Float16 h_lds[2][NH];  // double buffer
    __shared__ float red[8];                         // fallback fc partials

    const int b    = blockIdx.x;
    const int t    = threadIdx.x;   // 0..511
    const int kq   = t & 3;         // K-quarter (lane quad)
    const int unit = t >> 2;        // hidden unit 0..127

    // preload x row (512 x float4)
    ((float4*)x_lds)[t] = ((const float4*)(x + (size_t)b * NT))[t];
    if (t < NH) h_lds[0][t] = (_Float16)0.f;

    // weights: 4 gate rows of `unit`, K-slice [kq*32, kq*32+32) -> 4x16 half2
    unsigned wq[64];
    {
#pragma unroll
        for (int r = 0; r < 4; ++r) {
            const float2* p =
                (const float2*)(W_hh + (size_t)(r * NH + unit) * NH + kq * 32);
#pragma unroll
            for (int k = 0; k < 16; ++k) {
                float2 f = p[k];
                wq[r * 16 + k] = packh2(f.x, f.y);
            }
        }
    }
#pragma unroll
    for (int k = 0; k < 64; ++k) asm volatile("" : "+v"(wq[k]));

    // biases / x-weights (added once, post-combine, on all quad lanes)
    const float bi = b_ih[unit] + b_hh[unit];
    const float bf = b_ih[NH + unit] + b_hh[NH + unit];
    const float bz = b_ih[2 * NH + unit] + b_hh[2 * NH + unit];
    const float bo = b_ih[3 * NH + unit] + b_hh[3 * NH + unit];
    const float wi = W_ih[unit];
    const float wf = W_ih[NH + unit];
    const float wz = W_ih[2 * NH + unit];
    const float wo = W_ih[3 * NH + unit];

    float fcw = 0.f, fcb = 0.f;
    if (!DEFER_FC) {
        fcw = fc_w[unit];
        fcb = fc_b[0];
    }

    float c = 0.f, h = 0.f;  // replicated across the 4 quad lanes
    float*    outp = out + (size_t)b * NT;
    _Float16* hrow = DEFER_FC ? (hws + (size_t)b * NT * NH) : (_Float16*)nullptr;

    __syncthreads();

    for (int step = 0; step < NT; ++step) {
        const uint4* h4 = (const uint4*)h_lds[step & 1];
        float xv = x_lds[step];
        float si0 = 0.f, si1 = 0.f, sf0 = 0.f, sf1 = 0.f;
        float sz0 = 0.f, sz1 = 0.f, so0 = 0.f, so1 = 0.f;
#pragma unroll
        for (int j = 0; j < 4; ++j) {
            uint4 hv = h4[(kq << 2) + j];
            mix2(si0, wq[4 * j + 0], hv.x);
            mix2(si1, wq[4 * j + 1], hv.y);
            mix2(si0, wq[4 * j + 2], hv.z);
            mix2(si1, wq[4 * j + 3], hv.w);
            mix2(sf0, wq[16 + 4 * j + 0], hv.x);
            mix2(sf1, wq[16 + 4 * j + 1], hv.y);
            mix2(sf0, wq[16 + 4 * j + 2], hv.z);
            mix2(sf1, wq[16 + 4 * j + 3], hv.w);
            mix2(sz0, wq[32 + 4 * j + 0], hv.x);
            mix2(sz1, wq[32 + 4 * j + 1], hv.y);
            mix2(sz0, wq[32 + 4 * j + 2], hv.z);
            mix2(sz1, wq[32 + 4 * j + 3], hv.w);
            mix2(so0, wq[48 + 4 * j + 0], hv.x);
            mix2(so1, wq[48 + 4 * j + 1], hv.y);
            mix2(so0, wq[48 + 4 * j + 2], hv.z);
            mix2(so1, wq[48 + 4 * j + 3], hv.w);
        }
        float si = si0 + si1, sf = sf0 + sf1, sz = sz0 + sz1, so = so0 + so1;
        // quad butterfly on the VALU pipe (DPP quad_perm), not ds_bpermute
        si = dpp_add<0xB1>(si);
        sf = dpp_add<0xB1>(sf);
        sz = dpp_add<0xB1>(sz);
        so = dpp_add<0xB1>(so);
        si = dpp_add<0x4E>(si);
        sf = dpp_add<0x4E>(sf);
        sz = dpp_add<0x4E>(sz);
        so = dpp_add<0x4E>(so);
        si = fmaf(xv, wi, si + bi);
        sf = fmaf(xv, wf, sf + bf);
        sz = fmaf(xv, wz, sz + bz);
        so = fmaf(xv, wo, so + bo);
        // cell update, redundantly on all 4 quad lanes (identical results)
        float gi = fsig(si), gf = fsig(sf), gz = ftanh(sz), go = fsig(so);
        c = fmaf(gf, c, gi * gz);
        h = go * ftanh(c);
        if (kq == 0) {
            h_lds[(step + 1) & 1][unit] = (_Float16)h;
            if (DEFER_FC) hrow[(size_t)step * NH + unit] = (_Float16)h;
        }
        if (!DEFER_FC) {
            float p = (kq == 0) ? h * fcw : 0.f;
#pragma unroll
            for (int m = 32; m >= 1; m >>= 1) p += __shfl_xor(p, m, 64);
            if ((t & 63) == 0) red[t >> 6] = p;
            __syncthreads();
            if (t == 0) {
                float s = red[0] + red[1] + red[2] + red[3] + red[4] + red[5] +
                          red[6] + red[7];
                outp[step] = ftanh(s + fcb);
            }
        }
        barrier_lds();
    }

    // final hT, cT ([1,B,H] each, after out)
    if (kq == 0) {
        float* hT = out + (size_t)NB * NT;
        float* cT = hT + (size_t)NB * NH;
        hT[b * NH + unit] = h;
        cT[b * NH + unit] = c;
    }
}

// Kernel 2: out[b,t] = tanh(dot(h[b,t,:], fc_w) + fc_b). Memory-bound.
__global__ __launch_bounds__(256) void fc_k2(const _Float16* __restrict__ hws,
                                             const float* __restrict__ fc_w,
                                             const float* __restrict__ fc_b,
                                             float* __restrict__ out) {
    __shared__ unsigned wlds[64];
    const int t = threadIdx.x;
    if (t < 64) {
        float2 f = ((const float2*)fc_w)[t];
        wlds[t] = packh2(f.x, f.y);
    }
    __syncthreads();

    const size_t idx = (size_t)blockIdx.x * 256 + t;
    const uint4* hp = (const uint4*)(hws + idx * NH);
    const uint4* wp = (const uint4*)wlds;
    float acc = 0.f;
#pragma unroll
    for (int j = 0; j < 16; ++j) {
        uint4 hv = hp[j];
        uint4 wv = wp[j];
        acc = dot2(hv.x, wv.x, acc);
        acc = dot2(hv.y, wv.y, acc);
        acc = dot2(hv.z, wv.z, acc);
        acc = dot2(hv.w, wv.w, acc);
    }
    out[idx] = ftanh(acc + fc_b[0]);
}

extern "C" void kernel_launch(void* const* d_in, const int* in_sizes, int n_in,
                              void* d_out, int out_size, void* d_ws, size_t ws_size,
                              hipStream_t stream) {
    const float* x    = (const float*)d_in[0];
    const float* W_ih = (const float*)d_in[1];
    const float* W_hh = (const float*)d_in[2];
    const float* b_ih = (const float*)d_in[3];
    const float* b_hh = (const float*)d_in[4];
    const float* fc_w = (const float*)d_in[5];
    const float* fc_b = (const float*)d_in[6];
    float* out = (float*)d_out;

    const size_t need = (size_t)NB * NT * NH * sizeof(_Float16);  // 128 MB
    if (ws_size >= need) {
        _Float16* hws = (_Float16*)d_ws;
        lstm_k1<true><<<dim3(NB), dim3(512), 0, stream>>>(
            x, W_ih, W_hh, b_ih, b_hh, fc_w, fc_b, out, hws);
        fc_k2<<<dim3(NB * NT / 256), dim3(256), 0, stream>>>(hws, fc_w, fc_b, out);
    } else {
        lstm_k1<false><<<dim3(NB), dim3(512), 0, stream>>>(
            x, W_ih, W_hh, b_ih, b_hh, fc_w, fc_b, out, nullptr);
    }
}

// Round 8
// 1269.176 us; speedup vs baseline: 1.3915x; 1.3915x over previous
//
#include <hip/hip_runtime.h>

// LSTM B=256, T=2048, H=128. One batch row per WG, 512 threads = 128 units
// x 4 K-quarters. Thread (unit,kq) holds the kq*32..+32 slice of ALL FOUR
// gate rows (i,f,z,o) of its unit as 128 fp32 VGPRs, asm-pinned.
//
// Round-7 lesson: every f16 VALU MAC on gfx950 is ~quarter-rate
// (v_dot2_f32_f16 ~8 cyc, v_fma_mix_f32 ~6-7 cyc). Plain v_fma_f32 is the
// ONLY verified full-rate MAC (2 cyc/wave-instr). So: fp32 weights, fp32 h,
// 128 v_fma_f32 per thread per step — half the VALU cycles of the dot2 path.
//
// h_lds stores fp32 in 4 padded 36-float slices (stride 144B) so the four
// kq quads read DISJOINT bank groups (16-lane broadcast within each quad).
// Per step (ONE lgkmcnt-only barrier): 8x ds_read_b128 -> 128 v_fma_f32
// (4-gate round-robin, dep gap 8 cyc) -> 8 DPP quad_perm adds -> bias/x ->
// activations + cell update redundantly on quad lanes -> kq==0 writes h to
// double-buffered h_lds + fire-and-forget fp16 store to d_ws. fc in kernel 2.

typedef _Float16 half2v __attribute__((ext_vector_type(2)));

constexpr int NB = 256;
constexpr int NT = 2048;
constexpr int NH = 128;

__device__ __forceinline__ float fexp2(float x) {
    float r;
    asm("v_exp_f32 %0, %1" : "=v"(r) : "v"(x));
    return r;
}
__device__ __forceinline__ float frcp(float x) {
    float r;
    asm("v_rcp_f32 %0, %1" : "=v"(r) : "v"(x));
    return r;
}
__device__ __forceinline__ float fsig(float x) {   // 1/(1+2^(-x*log2e))
    return frcp(1.f + fexp2(x * -1.44269504f));
}
__device__ __forceinline__ float ftanh(float x) {  // 2/(1+2^(-2x*log2e)) - 1
    return fmaf(2.f, frcp(1.f + fexp2(x * -2.88539008f)), -1.f);
}

// v += (v from quad_perm<CTRL> lane) — pure VALU (DPP), no LDS pipe.
// 0xB1 = [1,0,3,2] (xor 1), 0x4E = [2,3,0,1] (xor 2).
template <int CTRL>
__device__ __forceinline__ float dpp_add(float v) {
    int s = __builtin_bit_cast(int, v);
    int p = __builtin_amdgcn_update_dpp(s, s, CTRL, 0xF, 0xF, false);
    return v + __builtin_bit_cast(float, p);
}

__device__ __forceinline__ unsigned packh2(float lo, float hi) {
    half2v p;
    p.x = (_Float16)lo;
    p.y = (_Float16)hi;
    return __builtin_bit_cast(unsigned, p);
}

__device__ __forceinline__ float dot2(unsigned int w, unsigned int h, float acc) {
    half2v a = __builtin_bit_cast(half2v, w);
    half2v b = __builtin_bit_cast(half2v, h);
#if __has_builtin(__builtin_amdgcn_fdot2)
    return __builtin_amdgcn_fdot2(a, b, acc, false);
#else
    float r;
    asm("v_dot2_f32_f16 %0, %1, %2, %3" : "=v"(r) : "v"(a), "v"(b), "v"(acc));
    return r;
#endif
}

// barrier with LDS visibility, NO vmcnt drain (fire-and-forget h stores
// stay off the 2048-iteration critical path)
__device__ __forceinline__ void barrier_lds() {
    asm volatile("s_waitcnt lgkmcnt(0)" ::: "memory");
    __builtin_amdgcn_s_barrier();
    asm volatile("" ::: "memory");
}

// padded fp32 h slice layout: slice kq at floats [kq*36, kq*36+32)
__device__ __forceinline__ int h_idx(int u) { return (u >> 5) * 36 + (u & 31); }

template <bool DEFER_FC>
__global__ __launch_bounds__(512) __attribute__((amdgpu_waves_per_eu(2, 2)))
void lstm_k1(const float* __restrict__ x, const float* __restrict__ W_ih,
             const float* __restrict__ W_hh, const float* __restrict__ b_ih,
             const float* __restrict__ b_hh, const float* __restrict__ fc_w,
             const float* __restrict__ fc_b, float* __restrict__ out,
             _Float16* __restrict__ hws) {
    __shared__ __align__(16) float x_lds[NT];
    __shared__ __align__(16) float h_lds[2][4 * 36];  // padded, double buffer
    __shared__ float red[8];                          // fallback fc partials

    const int b    = blockIdx.x;
    const int t    = threadIdx.x;   // 0..511
    const int kq   = t & 3;         // K-quarter (lane quad)
    const int unit = t >> 2;        // hidden unit 0..127

    // preload x row (512 x float4)
    ((float4*)x_lds)[t] = ((const float4*)(x + (size_t)b * NT))[t];
    if (t < NH) h_lds[0][h_idx(t)] = 0.f;

    // weights: 4 gate rows of `unit`, K-slice [kq*32, kq*32+32) -> 128 fp32
    float wq[128];
    {
#pragma unroll
        for (int r = 0; r < 4; ++r) {
            const float4* p =
                (const float4*)(W_hh + (size_t)(r * NH + unit) * NH + kq * 32);
#pragma unroll
            for (int j = 0; j < 8; ++j) {
                float4 f = p[j];
                wq[r * 32 + 4 * j + 0] = f.x;
                wq[r * 32 + 4 * j + 1] = f.y;
                wq[r * 32 + 4 * j + 2] = f.z;
                wq[r * 32 + 4 * j + 3] = f.w;
            }
        }
    }
#pragma unroll
    for (int k = 0; k < 128; ++k) asm volatile("" : "+v"(wq[k]));

    // biases / x-weights (added once, post-combine, on all quad lanes)
    const float bi = b_ih[unit] + b_hh[unit];
    const float bf = b_ih[NH + unit] + b_hh[NH + unit];
    const float bz = b_ih[2 * NH + unit] + b_hh[2 * NH + unit];
    const float bo = b_ih[3 * NH + unit] + b_hh[3 * NH + unit];
    const float wi = W_ih[unit];
    const float wf = W_ih[NH + unit];
    const float wz = W_ih[2 * NH + unit];
    const float wo = W_ih[3 * NH + unit];

    float fcw = 0.f, fcb = 0.f;
    if (!DEFER_FC) {
        fcw = fc_w[unit];
        fcb = fc_b[0];
    }

    float c = 0.f, h = 0.f;  // replicated across the 4 quad lanes
    float*    outp = out + (size_t)b * NT;
    _Float16* hrow = DEFER_FC ? (hws + (size_t)b * NT * NH) : (_Float16*)nullptr;

    __syncthreads();

    for (int step = 0; step < NT; ++step) {
        const float4* h4 = (const float4*)(h_lds[step & 1] + kq * 36);
        float xv = x_lds[step];
        float si = 0.f, sf = 0.f, sz = 0.f, so = 0.f;
#pragma unroll
        for (int j = 0; j < 8; ++j) {
            float4 hv = h4[j];
            // 4-gate round-robin: dependent-use gap = 4 instrs (8 cyc) > fma lat
            si = fmaf(wq[4 * j + 0], hv.x, si);
            sf = fmaf(wq[32 + 4 * j + 0], hv.x, sf);
            sz = fmaf(wq[64 + 4 * j + 0], hv.x, sz);
            so = fmaf(wq[96 + 4 * j + 0], hv.x, so);
            si = fmaf(wq[4 * j + 1], hv.y, si);
            sf = fmaf(wq[32 + 4 * j + 1], hv.y, sf);
            sz = fmaf(wq[64 + 4 * j + 1], hv.y, sz);
            so = fmaf(wq[96 + 4 * j + 1], hv.y, so);
            si = fmaf(wq[4 * j + 2], hv.z, si);
            sf = fmaf(wq[32 + 4 * j + 2], hv.z, sf);
            sz = fmaf(wq[64 + 4 * j + 2], hv.z, sz);
            so = fmaf(wq[96 + 4 * j + 2], hv.z, so);
            si = fmaf(wq[4 * j + 3], hv.w, si);
            sf = fmaf(wq[32 + 4 * j + 3], hv.w, sf);
            sz = fmaf(wq[64 + 4 * j + 3], hv.w, sz);
            so = fmaf(wq[96 + 4 * j + 3], hv.w, so);
        }
        // quad butterfly on the VALU pipe (DPP quad_perm)
        si = dpp_add<0xB1>(si);
        sf = dpp_add<0xB1>(sf);
        sz = dpp_add<0xB1>(sz);
        so = dpp_add<0xB1>(so);
        si = dpp_add<0x4E>(si);
        sf = dpp_add<0x4E>(sf);
        sz = dpp_add<0x4E>(sz);
        so = dpp_add<0x4E>(so);
        si = fmaf(xv, wi, si + bi);
        sf = fmaf(xv, wf, sf + bf);
        sz = fmaf(xv, wz, sz + bz);
        so = fmaf(xv, wo, so + bo);
        // cell update, redundantly on all 4 quad lanes (identical results)
        float gi = fsig(si), gf = fsig(sf), gz = ftanh(sz), go = fsig(so);
        c = fmaf(gf, c, gi * gz);
        h = go * ftanh(c);
        if (kq == 0) {
            h_lds[(step + 1) & 1][h_idx(unit)] = h;
            if (DEFER_FC) hrow[(size_t)step * NH + unit] = (_Float16)h;
        }
        if (!DEFER_FC) {
            float p = (kq == 0) ? h * fcw : 0.f;
#pragma unroll
            for (int m = 32; m >= 1; m >>= 1) p += __shfl_xor(p, m, 64);
            if ((t & 63) == 0) red[t >> 6] = p;
            __syncthreads();
            if (t == 0) {
                float s = red[0] + red[1] + red[2] + red[3] + red[4] + red[5] +
                          red[6] + red[7];
                outp[step] = ftanh(s + fcb);
            }
        }
        barrier_lds();
    }

    // final hT, cT ([1,B,H] each, after out)
    if (kq == 0) {
        float* hT = out + (size_t)NB * NT;
        float* cT = hT + (size_t)NB * NH;
        hT[b * NH + unit] = h;
        cT[b * NH + unit] = c;
    }
}

// Kernel 2: out[b,t] = tanh(dot(h[b,t,:], fc_w) + fc_b). Memory-bound.
__global__ __launch_bounds__(256) void fc_k2(const _Float16* __restrict__ hws,
                                             const float* __restrict__ fc_w,
                                             const float* __restrict__ fc_b,
                                             float* __restrict__ out) {
    __shared__ unsigned wlds[64];
    const int t = threadIdx.x;
    if (t < 64) {
        float2 f = ((const float2*)fc_w)[t];
        wlds[t] = packh2(f.x, f.y);
    }
    __syncthreads();

    const size_t idx = (size_t)blockIdx.x * 256 + t;
    const uint4* hp = (const uint4*)(hws + idx * NH);
    const uint4* wp = (const uint4*)wlds;
    float acc = 0.f;
#pragma unroll
    for (int j = 0; j < 16; ++j) {
        uint4 hv = hp[j];
        uint4 wv = wp[j];
        acc = dot2(hv.x, wv.x, acc);
        acc = dot2(hv.y, wv.y, acc);
        acc = dot2(hv.z, wv.z, acc);
        acc = dot2(hv.w, wv.w, acc);
    }
    out[idx] = ftanh(acc + fc_b[0]);
}

extern "C" void kernel_launch(void* const* d_in, const int* in_sizes, int n_in,
                              void* d_out, int out_size, void* d_ws, size_t ws_size,
                              hipStream_t stream) {
    const float* x    = (const float*)d_in[0];
    const float* W_ih = (const float*)d_in[1];
    const float* W_hh = (const float*)d_in[2];
    const float* b_ih = (const float*)d_in[3];
    const float* b_hh = (const float*)d_in[4];
    const float* fc_w = (const float*)d_in[5];
    const float* fc_b = (const float*)d_in[6];
    float* out = (float*)d_out;

    const size_t need = (size_t)NB * NT * NH * sizeof(_Float16);  // 128 MB
    if (ws_size >= need) {
        _Float16* hws = (_Float16*)d_ws;
        lstm_k1<true><<<dim3(NB), dim3(512), 0, stream>>>(
            x, W_ih, W_hh, b_ih, b_hh, fc_w, fc_b, out, hws);
        fc_k2<<<dim3(NB * NT / 256), dim3(256), 0, stream>>>(hws, fc_w, fc_b, out);
    } else {
        lstm_k1<false><<<dim3(NB), dim3(512), 0, stream>>>(
            x, W_ih, W_hh, b_ih, b_hh, fc_w, fc_b, out, nullptr);
    }
}